// Round 4
// baseline (1397.634 us; speedup 1.0000x reference)
//
#include <hip/hip_runtime.h>

// ---------------------------------------------------------------------------
// GRUAgg: ragged groups -> dense [B,96,D] (timestamp-sorted, zero-padded head)
// -> 2-layer GRU (PyTorch gate order r,z,n) -> mean over 96 steps.
// B=2048, L=96, D=256, 3D=768, E=131072.
// Pipeline chunked at Tc=16 steps so xgA/h1buf/xgB (~116 MB) stay L3-resident:
// the xg round-trip never touches HBM (round-3 counters: 620 MB HBM writes).
// ---------------------------------------------------------------------------

typedef short bh8 __attribute__((ext_vector_type(8)));   // 8 bf16 in 4 VGPRs
typedef float f4  __attribute__((ext_vector_type(4)));   // MFMA accumulator

#define NB 2048
#define LT 96
#define DF 256
#define NG 768
#define TCHUNK 16

// h LDS frag layout: [kt(8)][lane(64)][j(8)] bf16; element (row,col) of h:
#define LHA(col, row) (((((col) >> 5) * 64 + (((col) >> 3) & 3) * 16 + (row)) * 8) + ((col) & 7))

static __device__ __forceinline__ unsigned short f2b(float f) {
  union { float f; unsigned int u; } v; v.f = f;
  unsigned int r = v.u + 0x7fffu + ((v.u >> 16) & 1u);   // RNE
  return (unsigned short)(r >> 16);
}
static __device__ __forceinline__ float b2f(unsigned short s) {
  union { unsigned int u; float f; } v; v.u = ((unsigned int)s) << 16; return v.f;
}
static __device__ __forceinline__ unsigned int pk2(float a, float b) {
  return (unsigned int)f2b(a) | ((unsigned int)f2b(b) << 16);
}
static __device__ __forceinline__ float sigm(float x) { return 1.0f / (1.0f + __expf(-x)); }
static __device__ __forceinline__ float tanh_(float x) { return 2.0f / (1.0f + __expf(-2.0f * x)) - 1.0f; }

// --------------------------- group offsets/counts ---------------------------
__global__ void k_offsets(const int* __restrict__ idx, int E,
                          int* __restrict__ offs, int* __restrict__ cnt) {
  int b = blockIdx.x * blockDim.x + threadIdx.x;
  if (b >= NB) return;
  int lo = 0, hi = E;
  while (lo < hi) { int m = (lo + hi) >> 1; if (idx[m] < b) lo = m + 1; else hi = m; }
  int lb = lo;
  lo = lb; hi = E;
  while (lo < hi) { int m = (lo + hi) >> 1; if (idx[m] < b + 1) lo = m + 1; else hi = m; }
  offs[b] = lb;
  cnt[b] = lo - lb;
}

// ------------- per-group stable timestamp rank -> slot permutation ----------
__global__ void k_rank(const float* __restrict__ ts, const int* __restrict__ offs,
                       const int* __restrict__ cnt, int* __restrict__ perm) {
  __shared__ float sts[96];
  int b = blockIdx.x, j = threadIdx.x;
  int o = offs[b];
  int c = cnt[b]; if (c > 96) c = 96;
  if (j < 96) perm[b * 96 + j] = -1;
  if (j < c) sts[j] = ts[o + j];
  __syncthreads();
  if (j < c) {
    float tj = sts[j];
    int rank = 0;
    for (int k = 0; k < c; ++k) {
      float tk = sts[k];
      rank += (tk < tj) || (tk == tj && k < j);
    }
    int slot = (tj > 0.0f ? (96 - c) : 0) + rank;
    perm[b * 96 + slot] = o + j;
  }
}

// ------------- pack 4 weight matrices into MFMA B-fragment order ------------
// value(nt,kt,lane,j) = W[n][k], n = nt*16+(lane&15), k = kt*32+(lane>>4)*8+j
// layout: [mat(4)][nt(48)][kt(8)][lane(64)][j(8)] bf16
__global__ void k_packw(const float* __restrict__ w0, const float* __restrict__ w1,
                        const float* __restrict__ w2, const float* __restrict__ w3,
                        unsigned short* __restrict__ wfrag) {
  int t = blockIdx.x * blockDim.x + threadIdx.x;
  if (t >= 4 * 48 * 8 * 64) return;
  int m = t / 24576;
  int r = t % 24576;
  int nt = r / 512;
  int kt = (r / 64) & 7;
  int lane = r & 63;
  int n = nt * 16 + (lane & 15);
  int kb = kt * 32 + (lane >> 4) * 8;
  const float* W = (m == 0) ? w0 : (m == 1) ? w1 : (m == 2) ? w2 : w3;
  unsigned int o[4];
#pragma unroll
  for (int p = 0; p < 4; ++p)
    o[p] = pk2(W[n * 256 + kb + 2 * p], W[n * 256 + kb + 2 * p + 1]);
  uint4 v; v.x = o[0]; v.y = o[1]; v.z = o[2]; v.w = o[3];
  *(uint4*)&wfrag[(size_t)t * 8] = v;
}

// --------------------------- input-projection GEMM --------------------------
// C[rows][768] = A[rows][256] @ W^T + bias, bf16 out, fp32 accum.
// Persistent: grid 6*jbN blocks; block (ntb, jb) holds its 2-ntile-per-wave B
// fragments in VGPRs and loops over 64-row slabs jb, jb+jbN, ... staging A
// through double-buffered LDS with register prefetch across slabs.
// A-frag LDS layout padded to 65x16B regions (region = msub*8+kt) so the
// staging ds_write_b128 bank-groups are uniform (round-3: 1.4e7 conflicts).
template <int AMODE>
__launch_bounds__(256, 2)
__global__ void k_xgemm(const float* __restrict__ Ax, const unsigned short* __restrict__ Ab,
                        const int* __restrict__ perm, int t0, int slabsTotal, int jbN,
                        const unsigned short* __restrict__ wfrag, const float* __restrict__ bias,
                        unsigned short* __restrict__ Cout) {
  // each buffer: A-frag bf16 (32 regions x 65 x 16 B = 33280 B) or fp32 slab
  // 64 x 140 (35840 B)
  __shared__ float lsm[2][8960];

  const int tid = threadIdx.x;
  const int ntb = blockIdx.x % 6;
  const int jb  = blockIdx.x / 6;
  if (jb >= slabsTotal) return;
  const int w = tid >> 6, l = tid & 63, lm = l & 15, lq = l >> 4;

  // B fragments resident in VGPRs: wave w owns ntiles 2w, 2w+1 of this ntb.
  const unsigned short* wfN = wfrag + (size_t)ntb * 32768;
  bh8 bf[2][8];
#pragma unroll
  for (int i = 0; i < 2; ++i)
#pragma unroll
    for (int kt = 0; kt < 8; ++kt)
      bf[i][kt] = *(const bh8*)&wfN[(((2 * w + i) * 8 + kt) * 64 + l) * 8];
  const float bias0 = bias[ntb * 128 + (2 * w + 0) * 16 + lm];
  const float bias1 = bias[ntb * 128 + (2 * w + 1) * 16 + lm];

  // staging geometry: thread covers row trow, float cols 64*tp .. 64*tp+63
  const int trow = tid >> 2, tp = tid & 3;
  const int msub = trow >> 4, rlm = trow & 15;

  f4 pf[16];      // AMODE 0 prefetch (fp32)
  uint4 pb[8];    // AMODE 1 prefetch (bf16)

  auto issue_loads = [&](int s) {
    int row = s * 64 + trow;
    if (AMODE == 0) {
      int tt = row >> 11, g = row & 2047;
      int src = perm[g * 96 + t0 + tt];
      if (src >= 0) {
        const float* p = Ax + (size_t)src * 256 + tp * 64;
#pragma unroll
        for (int i = 0; i < 16; ++i) pf[i] = *(const f4*)(p + 4 * i);
      } else {
#pragma unroll
        for (int i = 0; i < 16; ++i) pf[i] = (f4){0.f, 0.f, 0.f, 0.f};
      }
    } else {
      const unsigned short* p = Ab + (size_t)row * 256 + tp * 64;
#pragma unroll
      for (int i = 0; i < 8; ++i) pb[i] = *(const uint4*)(p + 8 * i);
    }
  };
  auto write_afrag = [&](int buf) {
    unsigned short* aN = (unsigned short*)lsm[buf];
#pragma unroll
    for (int kk = 0; kk < 2; ++kk)
#pragma unroll
      for (int rlq = 0; rlq < 4; ++rlq) {
        int kt = 2 * tp + kk;
        unsigned short* d = &aN[(((msub * 8 + kt) * 65) + rlq * 16 + rlm) * 8];
        if (AMODE == 0) {
          f4 f0 = pf[8 * kk + 2 * rlq], f1 = pf[8 * kk + 2 * rlq + 1];
          uint4 v;
          v.x = pk2(f0.x, f0.y); v.y = pk2(f0.z, f0.w);
          v.z = pk2(f1.x, f1.y); v.w = pk2(f1.z, f1.w);
          *(uint4*)d = v;
        } else {
          *(uint4*)d = pb[4 * kk + rlq];
        }
      }
  };

  // prologue: stage first slab
  issue_loads(jb);
  write_afrag(0);
  __syncthreads();

  int cur = 0;
  for (int s = jb; s < slabsTotal; s += jbN) {
    const int snext = s + jbN;
    const bool hasNext = snext < slabsTotal;
    if (hasNext) issue_loads(snext);

    // MFMA from buf[cur]
    const unsigned short* aC = (const unsigned short*)lsm[cur];
    f4 acc[4][2];
#pragma unroll
    for (int m = 0; m < 4; ++m)
#pragma unroll
      for (int n = 0; n < 2; ++n) acc[m][n] = (f4){0.f, 0.f, 0.f, 0.f};
#pragma unroll
    for (int kt = 0; kt < 8; ++kt) {
      bh8 a[4];
#pragma unroll
      for (int m = 0; m < 4; ++m) a[m] = *(const bh8*)&aC[(((m * 8 + kt) * 65) + l) * 8];
#pragma unroll
      for (int m = 0; m < 4; ++m) {
        acc[m][0] = __builtin_amdgcn_mfma_f32_16x16x32_bf16(a[m], bf[0][kt], acc[m][0], 0, 0, 0);
        acc[m][1] = __builtin_amdgcn_mfma_f32_16x16x32_bf16(a[m], bf[1][kt], acc[m][1], 0, 0, 0);
      }
    }

    // epilogue: acc + bias -> fp32 slab in buf[cur^1] (swizzled: phys = col + 4*(col>>5))
    float* sl = lsm[cur ^ 1];
#pragma unroll
    for (int m = 0; m < 4; ++m)
#pragma unroll
      for (int n = 0; n < 2; ++n) {
        int phys = 36 * w + 16 * n + lm;   // col = (2w+n)*16+lm, col>>5 == w
        float bv = n ? bias1 : bias0;
#pragma unroll
        for (int r = 0; r < 4; ++r)
          sl[(m * 16 + lq * 4 + r) * 140 + phys] = acc[m][n][r] + bv;
      }
    __syncthreads();

    // coalesced C store from slab: thread -> (trow, cols 32*tp..+31)
    {
      const float* sp = &sl[trow * 140 + 36 * tp];
      unsigned short* cp = &Cout[((size_t)s * 64 + trow) * NG + ntb * 128 + tp * 32];
#pragma unroll
      for (int i = 0; i < 4; ++i) {
        f4 v0 = *(const f4*)(sp + 8 * i), v1 = *(const f4*)(sp + 8 * i + 4);
        uint4 o;
        o.x = pk2(v0.x, v0.y); o.y = pk2(v0.z, v0.w);
        o.z = pk2(v1.x, v1.y); o.w = pk2(v1.z, v1.w);
        *(uint4*)(cp + 8 * i) = o;
      }
    }
    __syncthreads();

    if (hasNext) {
      write_afrag(cur ^ 1);
      __syncthreads();
    }
    cur ^= 1;
  }
}

// ------------------------------ recurrent core ------------------------------
// 256 blocks x 512 thr (8 waves), 1 block/CU. Block owns 8 groups (rows 0-7
// of the MFMA M=16 tile; rows 8-15 stay zero). Wave w owns h-cols
// {32w+lm, 32w+16+lm}: r ntiles 2w,2w+1 + z ntiles 16+2w,17+2w + n ntile
// 32+2w in VGPRs (160 regs); n ntile 33+2w streamed from LDS (64 KB).
// xg: contiguous 12 KB/step, reg-prefetched one step ahead into a
// double-buffered LDS slab; gate phase reads ds_read_u16 (no global scalars).
template <int LAYER>
__launch_bounds__(512, 2)
__global__ void k_recur(const unsigned short* __restrict__ wf, const float* __restrict__ bhh,
                        const unsigned short* __restrict__ xg, int Ta,
                        float* __restrict__ hstate, int first, int save,
                        unsigned short* __restrict__ h1out,
                        float* __restrict__ sumstate, float* __restrict__ outp, int last) {
  __shared__ __align__(16) unsigned short lBn[32768];     // 64 KB: n ntile 33+2w per wave
  __shared__ __align__(16) unsigned short lh[2][4096];    // 16 KB: h frags, double-buffered
  __shared__ __align__(16) unsigned short lxg[2][6144];   // 24 KB: xg slab, double-buffered

  const int tid = threadIdx.x;
  const int w = tid >> 6, l = tid & 63, lm = l & 15, lq = l >> 4;
  const int g0 = blockIdx.x * 8;
  const int col0 = w * 32 + lm, col1 = col0 + 16;
  const int act = (lq < 2);

  // VGPR-resident B fragments: r (2), z (2), n (1)
  bh8 br0[8], br1[8], bz0[8], bz1[8], bn0[8];
#pragma unroll
  for (int kt = 0; kt < 8; ++kt) {
    br0[kt] = *(const bh8*)&wf[(((2 * w + 0) * 8 + kt) * 64 + l) * 8];
    br1[kt] = *(const bh8*)&wf[(((2 * w + 1) * 8 + kt) * 64 + l) * 8];
    bz0[kt] = *(const bh8*)&wf[(((16 + 2 * w) * 8 + kt) * 64 + l) * 8];
    bz1[kt] = *(const bh8*)&wf[(((17 + 2 * w) * 8 + kt) * 64 + l) * 8];
    bn0[kt] = *(const bh8*)&wf[(((32 + 2 * w) * 8 + kt) * 64 + l) * 8];
  }
  const float bhr0 = bhh[col0], bhr1 = bhh[col1];
  const float bhz0 = bhh[256 + col0], bhz1 = bhh[256 + col1];
  const float bhn0 = bhh[512 + col0], bhn1 = bhh[512 + col1];

  {  // n ntile 33+2w' -> LDS
    for (int i = tid; i < 4096; i += 512) {
      int wp = i >> 9, kt = (i >> 6) & 7, lane = i & 63;
      ((uint4*)lBn)[i] = *(const uint4*)&wf[(((33 + 2 * wp) * 8 + kt) * 64 + lane) * 8];
    }
  }
  {  // zero both h buffers (rows 8-15 stay 0 forever)
    uint4 z; z.x = 0u; z.y = 0u; z.z = 0u; z.w = 0u;
    for (int i = tid; i < 1024; i += 512) ((uint4*)lh)[i] = z;
  }
  __syncthreads();

  float hp0[4], hp1[4], sm0[4], sm1[4];
  if (act) {
#pragma unroll
    for (int reg = 0; reg < 4; ++reg) {
      int row = lq * 4 + reg;
      float a0 = first ? 0.f : hstate[(size_t)(g0 + row) * DF + col0];
      float a1 = first ? 0.f : hstate[(size_t)(g0 + row) * DF + col1];
      hp0[reg] = a0; hp1[reg] = a1;
      lh[0][LHA(col0, row)] = f2b(a0);
      lh[0][LHA(col1, row)] = f2b(a1);
      if (LAYER == 1) {
        if (!first) {
          sm0[reg] = sumstate[(size_t)(g0 + row) * DF + col0];
          sm1[reg] = sumstate[(size_t)(g0 + row) * DF + col1];
        } else { sm0[reg] = 0.f; sm1[reg] = 0.f; }
      }
    }
  }
  {  // preload xg(0) into lxg[0]: contiguous 12288 B
    const unsigned short* gp = xg + (size_t)g0 * NG;
    uint4 q0 = *(const uint4*)(gp + tid * 8);
    *(uint4*)&lxg[0][tid * 8] = q0;
    if (tid < 256) {
      uint4 q1 = *(const uint4*)(gp + 4096 + tid * 8);
      *(uint4*)&lxg[0][4096 + tid * 8] = q1;
    }
  }
  __syncthreads();

  int cur = 0;
  for (int tt = 0; tt < Ta; ++tt) {
    const int nxt = cur ^ 1;
    // A) prefetch xg(tt+1) into regs (lands during this step's compute)
    uint4 p0, p1;
    const bool hasN = (tt + 1 < Ta);
    if (hasN) {
      const unsigned short* gp = xg + ((size_t)(tt + 1) * NB + g0) * NG;
      p0 = *(const uint4*)(gp + tid * 8);
      if (tid < 256) p1 = *(const uint4*)(gp + 4096 + tid * 8);
    }
    // B) cooperative h1out store of h(tt) (layer 0), overlaps MFMA
    if (LAYER == 0 && tt > 0 && tid < 256) {
      int row = tid >> 5, c0 = (tid & 31) * 8;
      uint4 hv = *(const uint4*)&lh[cur][(((c0 >> 5) * 64 + ((c0 >> 3) & 3) * 16 + row) * 8)];
      *(uint4*)&h1out[((size_t)(tt - 1) * NB + g0 + row) * DF + c0] = hv;
    }
    // C) MFMA: gates = h @ W_hh^T
    f4 ar0 = (f4){0.f,0.f,0.f,0.f}, ar1 = (f4){0.f,0.f,0.f,0.f};
    f4 az0 = (f4){0.f,0.f,0.f,0.f}, az1 = (f4){0.f,0.f,0.f,0.f};
    f4 an0 = (f4){0.f,0.f,0.f,0.f}, an1 = (f4){0.f,0.f,0.f,0.f};
    const unsigned short* hc = lh[cur];
#pragma unroll
    for (int kt = 0; kt < 8; ++kt) {
      bh8 a = *(const bh8*)&hc[(kt * 64 + l) * 8];
      ar0 = __builtin_amdgcn_mfma_f32_16x16x32_bf16(a, br0[kt], ar0, 0, 0, 0);
      ar1 = __builtin_amdgcn_mfma_f32_16x16x32_bf16(a, br1[kt], ar1, 0, 0, 0);
      az0 = __builtin_amdgcn_mfma_f32_16x16x32_bf16(a, bz0[kt], az0, 0, 0, 0);
      az1 = __builtin_amdgcn_mfma_f32_16x16x32_bf16(a, bz1[kt], az1, 0, 0, 0);
      an0 = __builtin_amdgcn_mfma_f32_16x16x32_bf16(a, bn0[kt], an0, 0, 0, 0);
      bh8 n1 = *(const bh8*)&lBn[((w * 8 + kt) * 64 + l) * 8];
      an1 = __builtin_amdgcn_mfma_f32_16x16x32_bf16(a, n1, an1, 0, 0, 0);
    }
    // D) gate phase: xg from LDS, write h(tt+1) -> lh[nxt]
    if (act) {
      const unsigned short* xc = lxg[cur];
#pragma unroll
      for (int reg = 0; reg < 4; ++reg) {
        int row = lq * 4 + reg;
        int base = row * NG;
        float xr0 = b2f(xc[base + col0]),       xr1 = b2f(xc[base + col1]);
        float xz0 = b2f(xc[base + 256 + col0]), xz1 = b2f(xc[base + 256 + col1]);
        float xn0 = b2f(xc[base + 512 + col0]), xn1 = b2f(xc[base + 512 + col1]);
        float r0 = sigm(xr0 + ar0[reg] + bhr0);
        float z0 = sigm(xz0 + az0[reg] + bhz0);
        float n0 = tanh_(xn0 + r0 * (an0[reg] + bhn0));
        float h0 = (1.f - z0) * n0 + z0 * hp0[reg]; hp0[reg] = h0;
        float r1 = sigm(xr1 + ar1[reg] + bhr1);
        float z1 = sigm(xz1 + az1[reg] + bhz1);
        float n1 = tanh_(xn1 + r1 * (an1[reg] + bhn1));
        float h1 = (1.f - z1) * n1 + z1 * hp1[reg]; hp1[reg] = h1;
        lh[nxt][LHA(col0, row)] = f2b(h0);
        lh[nxt][LHA(col1, row)] = f2b(h1);
        if (LAYER == 1) { sm0[reg] += h0; sm1[reg] += h1; }
      }
    }
    // E) commit xg prefetch to lxg[nxt]
    if (hasN) {
      *(uint4*)&lxg[nxt][tid * 8] = p0;
      if (tid < 256) *(uint4*)&lxg[nxt][4096 + tid * 8] = p1;
    }
    __syncthreads();
    cur = nxt;
  }

  // final h1out block (h(Ta))
  if (LAYER == 0 && tid < 256) {
    int row = tid >> 5, c0 = (tid & 31) * 8;
    uint4 hv = *(const uint4*)&lh[cur][(((c0 >> 5) * 64 + ((c0 >> 3) & 3) * 16 + row) * 8)];
    *(uint4*)&h1out[((size_t)(Ta - 1) * NB + g0 + row) * DF + c0] = hv;
  }
  if (act) {
    if (save) {
#pragma unroll
      for (int reg = 0; reg < 4; ++reg) {
        int row = lq * 4 + reg;
        hstate[(size_t)(g0 + row) * DF + col0] = hp0[reg];
        hstate[(size_t)(g0 + row) * DF + col1] = hp1[reg];
      }
    }
    if (LAYER == 1) {
      if (last) {
#pragma unroll
        for (int reg = 0; reg < 4; ++reg) {
          int row = lq * 4 + reg;
          outp[(size_t)(g0 + row) * DF + col0] = sm0[reg] * (1.0f / 96.0f);
          outp[(size_t)(g0 + row) * DF + col1] = sm1[reg] * (1.0f / 96.0f);
        }
      } else {
#pragma unroll
        for (int reg = 0; reg < 4; ++reg) {
          int row = lq * 4 + reg;
          sumstate[(size_t)(g0 + row) * DF + col0] = sm0[reg];
          sumstate[(size_t)(g0 + row) * DF + col1] = sm1[reg];
        }
      }
    }
  }
}

// ------------------------------- host launcher ------------------------------
extern "C" void kernel_launch(void* const* d_in, const int* in_sizes, int n_in,
                              void* d_out, int out_size, void* d_ws, size_t ws_size,
                              hipStream_t stream) {
  (void)n_in; (void)out_size;
  const float* x    = (const float*)d_in[0];
  const float* ts   = (const float*)d_in[1];
  const float* wih0 = (const float*)d_in[2];
  const float* whh0 = (const float*)d_in[3];
  const float* bih0 = (const float*)d_in[4];
  const float* bhh0 = (const float*)d_in[5];
  const float* wih1 = (const float*)d_in[6];
  const float* whh1 = (const float*)d_in[7];
  const float* bih1 = (const float*)d_in[8];
  const float* bhh1 = (const float*)d_in[9];
  const int*   idx  = (const int*)d_in[10];
  float* out = (float*)d_out;
  const int E = in_sizes[0] / DF;

  char* wsb = (char*)d_ws;
  size_t off = 0;
  auto carve = [&](size_t bytes) -> char* {
    off = (off + 255) & ~(size_t)255;
    char* p = wsb + off;
    off += bytes;
    return p;
  };
  int* offs = (int*)carve((size_t)NB * 4);
  int* cntp = (int*)carve((size_t)NB * 4);
  int* perm = (int*)carve((size_t)NB * LT * 4);
  unsigned short* wfrag = (unsigned short*)carve((size_t)4 * 196608 * 2);
  float* h0s  = (float*)carve((size_t)NB * DF * 4);
  float* h1s  = (float*)carve((size_t)NB * DF * 4);
  float* sums = (float*)carve((size_t)NB * DF * 4);
  size_t fixedBytes = off;

  const size_t perT = (size_t)NB * DF * 2 + 2 * (size_t)NB * NG * 2;  // 7,340,032 B
  int Tc = 1;
  if (ws_size > fixedBytes + 4096) {
    size_t t = (ws_size - fixedBytes - 4096) / perT;
    // cap at TCHUNK so xgA+h1buf+xgB (~116 MB) stay L3-resident per chunk
    Tc = (int)(t > TCHUNK ? TCHUNK : (t < 1 ? 1 : t));
  }
  unsigned short* h1buf = (unsigned short*)carve((size_t)Tc * NB * DF * 2);
  unsigned short* xgA   = (unsigned short*)carve((size_t)Tc * NB * NG * 2);
  unsigned short* xgB   = (unsigned short*)carve((size_t)Tc * NB * NG * 2);

  k_offsets<<<8, 256, 0, stream>>>(idx, E, offs, cntp);
  k_rank<<<NB, 128, 0, stream>>>(ts, offs, cntp, perm);
  k_packw<<<384, 256, 0, stream>>>(wih0, whh0, wih1, whh1, wfrag);

  for (int t0 = 0; t0 < LT; t0 += Tc) {
    int Ta = (LT - t0 < Tc) ? (LT - t0) : Tc;
    int first = (t0 == 0);
    int save = (t0 + Ta < LT);
    int last = (t0 + Ta == LT);
    int slabs = Ta * 32;
    // jbN: persistent-block stride; 6*jbN blocks, all co-resident (2/CU)
    int jbN = slabs < 85 ? slabs : 85;
    // layer 0 input projection (gathered x, pads -> b_ih)
    k_xgemm<0><<<dim3(6 * jbN), 256, 0, stream>>>(
        x, (const unsigned short*)nullptr, perm, t0, slabs, jbN, wfrag, bih0, xgA);
    // layer 0 recurrence -> h1buf
    k_recur<0><<<256, 512, 0, stream>>>(
        wfrag + 1 * 196608, bhh0, xgA, Ta, h0s, first, save, h1buf,
        (float*)nullptr, (float*)nullptr, 0);
    // layer 1 input projection (dense h1)
    k_xgemm<1><<<dim3(6 * jbN), 256, 0, stream>>>(
        (const float*)nullptr, h1buf, (const int*)nullptr, 0, slabs, jbN,
        wfrag + 2 * 196608, bih1, xgB);
    // layer 1 recurrence -> mean accumulation / output
    k_recur<1><<<256, 512, 0, stream>>>(
        wfrag + 3 * 196608, bhh1, xgB, Ta, h1s, first, save,
        (unsigned short*)nullptr, sums, out, last);
  }
}

// Round 5
// 1099.496 us; speedup vs baseline: 1.2712x; 1.2712x over previous
//
#include <hip/hip_runtime.h>

// ---------------------------------------------------------------------------
// GRUAgg: ragged groups -> dense [B,96,D] (timestamp-sorted, zero-padded head)
// -> 2-layer GRU (PyTorch gate order r,z,n) -> mean over 96 steps.
// B=2048, L=96, D=256, 3D=768, E=131072.
// Round-5: Tc reverted to 96 (Tc=16 chunking regressed: +12 launches and 6x
// W_hh frag reloads cost more than L3 residency saved). k_recur uses the
// duplicated-rows trick: h written to both row halves of the A-frag so MFMA
// C rows 8-15 duplicate rows 0-7, letting quads 2,3 compute col1 gates ->
// full-lane gate math, halved per-thread VALU/transcendental cost.
// ---------------------------------------------------------------------------

typedef short bh8 __attribute__((ext_vector_type(8)));   // 8 bf16 in 4 VGPRs
typedef float f4  __attribute__((ext_vector_type(4)));   // MFMA accumulator

#define NB 2048
#define LT 96
#define DF 256
#define NG 768

// h LDS frag layout: [kt(8)][lane(64)][j(8)] bf16; element (row,col) of h:
#define LHA(col, row) (((((col) >> 5) * 64 + (((col) >> 3) & 3) * 16 + (row)) * 8) + ((col) & 7))

static __device__ __forceinline__ unsigned short f2b(float f) {
  union { float f; unsigned int u; } v; v.f = f;
  unsigned int r = v.u + 0x7fffu + ((v.u >> 16) & 1u);   // RNE
  return (unsigned short)(r >> 16);
}
static __device__ __forceinline__ float b2f(unsigned short s) {
  union { unsigned int u; float f; } v; v.u = ((unsigned int)s) << 16; return v.f;
}
static __device__ __forceinline__ unsigned int pk2(float a, float b) {
  return (unsigned int)f2b(a) | ((unsigned int)f2b(b) << 16);
}
static __device__ __forceinline__ float sigm(float x) { return 1.0f / (1.0f + __expf(-x)); }
static __device__ __forceinline__ float tanh_(float x) { return 2.0f / (1.0f + __expf(-2.0f * x)) - 1.0f; }

// --------------------------- group offsets/counts ---------------------------
__global__ void k_offsets(const int* __restrict__ idx, int E,
                          int* __restrict__ offs, int* __restrict__ cnt) {
  int b = blockIdx.x * blockDim.x + threadIdx.x;
  if (b >= NB) return;
  int lo = 0, hi = E;
  while (lo < hi) { int m = (lo + hi) >> 1; if (idx[m] < b) lo = m + 1; else hi = m; }
  int lb = lo;
  lo = lb; hi = E;
  while (lo < hi) { int m = (lo + hi) >> 1; if (idx[m] < b + 1) lo = m + 1; else hi = m; }
  offs[b] = lb;
  cnt[b] = lo - lb;
}

// ------------- per-group stable timestamp rank -> slot permutation ----------
__global__ void k_rank(const float* __restrict__ ts, const int* __restrict__ offs,
                       const int* __restrict__ cnt, int* __restrict__ perm) {
  __shared__ float sts[96];
  int b = blockIdx.x, j = threadIdx.x;
  int o = offs[b];
  int c = cnt[b]; if (c > 96) c = 96;
  if (j < 96) perm[b * 96 + j] = -1;
  if (j < c) sts[j] = ts[o + j];
  __syncthreads();
  if (j < c) {
    float tj = sts[j];
    int rank = 0;
    for (int k = 0; k < c; ++k) {
      float tk = sts[k];
      rank += (tk < tj) || (tk == tj && k < j);
    }
    int slot = (tj > 0.0f ? (96 - c) : 0) + rank;
    perm[b * 96 + slot] = o + j;
  }
}

// ------------- pack 4 weight matrices into MFMA B-fragment order ------------
// value(nt,kt,lane,j) = W[n][k], n = nt*16+(lane&15), k = kt*32+(lane>>4)*8+j
// layout: [mat(4)][nt(48)][kt(8)][lane(64)][j(8)] bf16
__global__ void k_packw(const float* __restrict__ w0, const float* __restrict__ w1,
                        const float* __restrict__ w2, const float* __restrict__ w3,
                        unsigned short* __restrict__ wfrag) {
  int t = blockIdx.x * blockDim.x + threadIdx.x;
  if (t >= 4 * 48 * 8 * 64) return;
  int m = t / 24576;
  int r = t % 24576;
  int nt = r / 512;
  int kt = (r / 64) & 7;
  int lane = r & 63;
  int n = nt * 16 + (lane & 15);
  int kb = kt * 32 + (lane >> 4) * 8;
  const float* W = (m == 0) ? w0 : (m == 1) ? w1 : (m == 2) ? w2 : w3;
  unsigned int o[4];
#pragma unroll
  for (int p = 0; p < 4; ++p)
    o[p] = pk2(W[n * 256 + kb + 2 * p], W[n * 256 + kb + 2 * p + 1]);
  uint4 v; v.x = o[0]; v.y = o[1]; v.z = o[2]; v.w = o[3];
  *(uint4*)&wfrag[(size_t)t * 8] = v;
}

// --------------------------- input-projection GEMM --------------------------
// C[rows][768] = A[rows][256] @ W^T + bias, bf16 out, fp32 accum.
// Persistent: grid 6*jbN blocks; block (ntb, jb) holds its 2-ntile-per-wave B
// fragments in VGPRs and loops over 64-row slabs jb, jb+jbN, ... staging A
// through double-buffered LDS with register prefetch across slabs.
// A-frag LDS layout padded to 65x16B regions (region = msub*8+kt) so the
// staging ds_write_b128 bank-groups are uniform (round-3: 1.4e7 conflicts).
template <int AMODE>
__launch_bounds__(256, 2)
__global__ void k_xgemm(const float* __restrict__ Ax, const unsigned short* __restrict__ Ab,
                        const int* __restrict__ perm, int t0, int slabsTotal, int jbN,
                        const unsigned short* __restrict__ wfrag, const float* __restrict__ bias,
                        unsigned short* __restrict__ Cout) {
  // each buffer: A-frag bf16 (32 regions x 65 x 16 B = 33280 B) or fp32 slab
  // 64 x 140 (35840 B)
  __shared__ float lsm[2][8960];

  const int tid = threadIdx.x;
  const int ntb = blockIdx.x % 6;
  const int jb  = blockIdx.x / 6;
  if (jb >= slabsTotal) return;
  const int w = tid >> 6, l = tid & 63, lm = l & 15, lq = l >> 4;

  // B fragments resident in VGPRs: wave w owns ntiles 2w, 2w+1 of this ntb.
  const unsigned short* wfN = wfrag + (size_t)ntb * 32768;
  bh8 bf[2][8];
#pragma unroll
  for (int i = 0; i < 2; ++i)
#pragma unroll
    for (int kt = 0; kt < 8; ++kt)
      bf[i][kt] = *(const bh8*)&wfN[(((2 * w + i) * 8 + kt) * 64 + l) * 8];
  const float bias0 = bias[ntb * 128 + (2 * w + 0) * 16 + lm];
  const float bias1 = bias[ntb * 128 + (2 * w + 1) * 16 + lm];

  // staging geometry: thread covers row trow, float cols 64*tp .. 64*tp+63
  const int trow = tid >> 2, tp = tid & 3;
  const int msub = trow >> 4, rlm = trow & 15;

  f4 pf[16];      // AMODE 0 prefetch (fp32)
  uint4 pb[8];    // AMODE 1 prefetch (bf16)

  auto issue_loads = [&](int s) {
    int row = s * 64 + trow;
    if (AMODE == 0) {
      int tt = row >> 11, g = row & 2047;
      int src = perm[g * 96 + t0 + tt];
      if (src >= 0) {
        const float* p = Ax + (size_t)src * 256 + tp * 64;
#pragma unroll
        for (int i = 0; i < 16; ++i) pf[i] = *(const f4*)(p + 4 * i);
      } else {
#pragma unroll
        for (int i = 0; i < 16; ++i) pf[i] = (f4){0.f, 0.f, 0.f, 0.f};
      }
    } else {
      const unsigned short* p = Ab + (size_t)row * 256 + tp * 64;
#pragma unroll
      for (int i = 0; i < 8; ++i) pb[i] = *(const uint4*)(p + 8 * i);
    }
  };
  auto write_afrag = [&](int buf) {
    unsigned short* aN = (unsigned short*)lsm[buf];
#pragma unroll
    for (int kk = 0; kk < 2; ++kk)
#pragma unroll
      for (int rlq = 0; rlq < 4; ++rlq) {
        int kt = 2 * tp + kk;
        unsigned short* d = &aN[(((msub * 8 + kt) * 65) + rlq * 16 + rlm) * 8];
        if (AMODE == 0) {
          f4 f0 = pf[8 * kk + 2 * rlq], f1 = pf[8 * kk + 2 * rlq + 1];
          uint4 v;
          v.x = pk2(f0.x, f0.y); v.y = pk2(f0.z, f0.w);
          v.z = pk2(f1.x, f1.y); v.w = pk2(f1.z, f1.w);
          *(uint4*)d = v;
        } else {
          *(uint4*)d = pb[4 * kk + rlq];
        }
      }
  };

  // prologue: stage first slab
  issue_loads(jb);
  write_afrag(0);
  __syncthreads();

  int cur = 0;
  for (int s = jb; s < slabsTotal; s += jbN) {
    const int snext = s + jbN;
    const bool hasNext = snext < slabsTotal;
    if (hasNext) issue_loads(snext);

    // MFMA from buf[cur]
    const unsigned short* aC = (const unsigned short*)lsm[cur];
    f4 acc[4][2];
#pragma unroll
    for (int m = 0; m < 4; ++m)
#pragma unroll
      for (int n = 0; n < 2; ++n) acc[m][n] = (f4){0.f, 0.f, 0.f, 0.f};
#pragma unroll
    for (int kt = 0; kt < 8; ++kt) {
      bh8 a[4];
#pragma unroll
      for (int m = 0; m < 4; ++m) a[m] = *(const bh8*)&aC[(((m * 8 + kt) * 65) + l) * 8];
#pragma unroll
      for (int m = 0; m < 4; ++m) {
        acc[m][0] = __builtin_amdgcn_mfma_f32_16x16x32_bf16(a[m], bf[0][kt], acc[m][0], 0, 0, 0);
        acc[m][1] = __builtin_amdgcn_mfma_f32_16x16x32_bf16(a[m], bf[1][kt], acc[m][1], 0, 0, 0);
      }
    }

    // epilogue: acc + bias -> fp32 slab in buf[cur^1] (swizzled: phys = col + 4*(col>>5))
    float* sl = lsm[cur ^ 1];
#pragma unroll
    for (int m = 0; m < 4; ++m)
#pragma unroll
      for (int n = 0; n < 2; ++n) {
        int phys = 36 * w + 16 * n + lm;   // col = (2w+n)*16+lm, col>>5 == w
        float bv = n ? bias1 : bias0;
#pragma unroll
        for (int r = 0; r < 4; ++r)
          sl[(m * 16 + lq * 4 + r) * 140 + phys] = acc[m][n][r] + bv;
      }
    __syncthreads();

    // coalesced C store from slab: thread -> (trow, cols 32*tp..+31)
    {
      const float* sp = &sl[trow * 140 + 36 * tp];
      unsigned short* cp = &Cout[((size_t)s * 64 + trow) * NG + ntb * 128 + tp * 32];
#pragma unroll
      for (int i = 0; i < 4; ++i) {
        f4 v0 = *(const f4*)(sp + 8 * i), v1 = *(const f4*)(sp + 8 * i + 4);
        uint4 o;
        o.x = pk2(v0.x, v0.y); o.y = pk2(v0.z, v0.w);
        o.z = pk2(v1.x, v1.y); o.w = pk2(v1.z, v1.w);
        *(uint4*)(cp + 8 * i) = o;
      }
    }
    __syncthreads();

    if (hasNext) {
      write_afrag(cur ^ 1);
      __syncthreads();
    }
    cur ^= 1;
  }
}

// ------------------------------ recurrent core ------------------------------
// 256 blocks x 512 thr (8 waves), 1 block/CU. Block owns 8 groups. h is
// DUPLICATED into both row halves (rows 0-7 == rows 8-15) of the A-frag, so
// every MFMA C tile carries the same answer in quads 0,1 (rows 0-7) and
// quads 2,3 (rows 8-15). Quads 0,1 compute gates for col0 = w*32+lm from
// ar0/az0/an0; quads 2,3 compute col1 = col0+16 from ar1/az1/an1 -> all 64
// lanes do gate math, 4 gate-sets per thread (halved VALU/transcendentals).
// Wave w: r ntiles 2w,2w+1 + z ntiles 16+2w,17+2w + n ntile 32+2w in VGPRs
// (160 regs); n ntile 33+2w streamed from LDS (64 KB).
// xg: contiguous 12 KB/step, reg-prefetched one step ahead into a
// double-buffered LDS slab; gate phase reads ds_read_u16 (no global scalars).
template <int LAYER>
__launch_bounds__(512, 2)
__global__ void k_recur(const unsigned short* __restrict__ wf, const float* __restrict__ bhh,
                        const unsigned short* __restrict__ xg, int Ta,
                        float* __restrict__ hstate, int first, int save,
                        unsigned short* __restrict__ h1out,
                        float* __restrict__ sumstate, float* __restrict__ outp, int last) {
  __shared__ __align__(16) unsigned short lBn[32768];     // 64 KB: n ntile 33+2w per wave
  __shared__ __align__(16) unsigned short lh[2][4096];    // 16 KB: h frags, double-buffered
  __shared__ __align__(16) unsigned short lxg[2][6144];   // 24 KB: xg slab, double-buffered

  const int tid = threadIdx.x;
  const int w = tid >> 6, l = tid & 63, lm = l & 15, lq = l >> 4;
  const int g0 = blockIdx.x * 8;
  const int colA = w * 32 + lm;
  const int mycol = (lq < 2) ? colA : (colA + 16);   // quad-half owns one col
  const int rlow = (lq & 1) * 4;                     // rows rlow..rlow+3

  // VGPR-resident B fragments: r (2), z (2), n (1)
  bh8 br0[8], br1[8], bz0[8], bz1[8], bn0[8];
#pragma unroll
  for (int kt = 0; kt < 8; ++kt) {
    br0[kt] = *(const bh8*)&wf[(((2 * w + 0) * 8 + kt) * 64 + l) * 8];
    br1[kt] = *(const bh8*)&wf[(((2 * w + 1) * 8 + kt) * 64 + l) * 8];
    bz0[kt] = *(const bh8*)&wf[(((16 + 2 * w) * 8 + kt) * 64 + l) * 8];
    bz1[kt] = *(const bh8*)&wf[(((17 + 2 * w) * 8 + kt) * 64 + l) * 8];
    bn0[kt] = *(const bh8*)&wf[(((32 + 2 * w) * 8 + kt) * 64 + l) * 8];
  }
  const float bhr = bhh[mycol];
  const float bhz = bhh[256 + mycol];
  const float bhn = bhh[512 + mycol];

  {  // n ntile 33+2w' -> LDS
    for (int i = tid; i < 4096; i += 512) {
      int wp = i >> 9, kt = (i >> 6) & 7, lane = i & 63;
      ((uint4*)lBn)[i] = *(const uint4*)&wf[(((33 + 2 * wp) * 8 + kt) * 64 + lane) * 8];
    }
  }
  {  // zero both h buffers
    uint4 z; z.x = 0u; z.y = 0u; z.z = 0u; z.w = 0u;
    for (int i = tid; i < 1024; i += 512) ((uint4*)lh)[i] = z;
  }
  __syncthreads();

  float hp[4], sm[4];
#pragma unroll
  for (int reg = 0; reg < 4; ++reg) {
    int row = rlow + reg;
    float a = first ? 0.f : hstate[(size_t)(g0 + row) * DF + mycol];
    hp[reg] = a;
    lh[0][LHA(mycol, row)] = f2b(a);
    lh[0][LHA(mycol, row + 8)] = f2b(a);   // duplicated row half
    if (LAYER == 1) {
      sm[reg] = (!first) ? sumstate[(size_t)(g0 + row) * DF + mycol] : 0.f;
    }
  }
  {  // preload xg(0) into lxg[0]: contiguous 12288 B
    const unsigned short* gp = xg + (size_t)g0 * NG;
    uint4 q0 = *(const uint4*)(gp + tid * 8);
    *(uint4*)&lxg[0][tid * 8] = q0;
    if (tid < 256) {
      uint4 q1 = *(const uint4*)(gp + 4096 + tid * 8);
      *(uint4*)&lxg[0][4096 + tid * 8] = q1;
    }
  }
  __syncthreads();

  int cur = 0;
  for (int tt = 0; tt < Ta; ++tt) {
    const int nxt = cur ^ 1;
    // A) prefetch xg(tt+1) into regs (lands during this step's compute)
    uint4 p0, p1;
    const bool hasN = (tt + 1 < Ta);
    if (hasN) {
      const unsigned short* gp = xg + ((size_t)(tt + 1) * NB + g0) * NG;
      p0 = *(const uint4*)(gp + tid * 8);
      if (tid < 256) p1 = *(const uint4*)(gp + 4096 + tid * 8);
    }
    // B) cooperative h1out store of h(tt) (layer 0), overlaps MFMA
    if (LAYER == 0 && tt > 0 && tid < 256) {
      int row = tid >> 5, c0 = (tid & 31) * 8;
      uint4 hv = *(const uint4*)&lh[cur][(((c0 >> 5) * 64 + ((c0 >> 3) & 3) * 16 + row) * 8)];
      *(uint4*)&h1out[((size_t)(tt - 1) * NB + g0 + row) * DF + c0] = hv;
    }
    // C) MFMA: gates = h @ W_hh^T (rows duplicated -> both quad-halves valid)
    f4 ar0 = (f4){0.f,0.f,0.f,0.f}, ar1 = (f4){0.f,0.f,0.f,0.f};
    f4 az0 = (f4){0.f,0.f,0.f,0.f}, az1 = (f4){0.f,0.f,0.f,0.f};
    f4 an0 = (f4){0.f,0.f,0.f,0.f}, an1 = (f4){0.f,0.f,0.f,0.f};
    const unsigned short* hc = lh[cur];
#pragma unroll
    for (int kt = 0; kt < 8; ++kt) {
      bh8 a = *(const bh8*)&hc[(kt * 64 + l) * 8];
      ar0 = __builtin_amdgcn_mfma_f32_16x16x32_bf16(a, br0[kt], ar0, 0, 0, 0);
      ar1 = __builtin_amdgcn_mfma_f32_16x16x32_bf16(a, br1[kt], ar1, 0, 0, 0);
      az0 = __builtin_amdgcn_mfma_f32_16x16x32_bf16(a, bz0[kt], az0, 0, 0, 0);
      az1 = __builtin_amdgcn_mfma_f32_16x16x32_bf16(a, bz1[kt], az1, 0, 0, 0);
      an0 = __builtin_amdgcn_mfma_f32_16x16x32_bf16(a, bn0[kt], an0, 0, 0, 0);
      bh8 n1 = *(const bh8*)&lBn[((w * 8 + kt) * 64 + l) * 8];
      an1 = __builtin_amdgcn_mfma_f32_16x16x32_bf16(a, n1, an1, 0, 0, 0);
    }
    // D) gate phase: all lanes active, one col each; select this quad's acc
    {
      f4 aR = (lq < 2) ? ar0 : ar1;
      f4 aZ = (lq < 2) ? az0 : az1;
      f4 aN = (lq < 2) ? an0 : an1;
      const unsigned short* xc = lxg[cur];
      unsigned short* hn = lh[nxt];
#pragma unroll
      for (int reg = 0; reg < 4; ++reg) {
        int row = rlow + reg;
        int base = row * NG + mycol;
        float xr = b2f(xc[base]);
        float xz = b2f(xc[base + 256]);
        float xn = b2f(xc[base + 512]);
        float r = sigm(xr + aR[reg] + bhr);
        float z = sigm(xz + aZ[reg] + bhz);
        float n = tanh_(xn + r * (aN[reg] + bhn));
        float h = (1.f - z) * n + z * hp[reg]; hp[reg] = h;
        unsigned short hb = f2b(h);
        hn[LHA(mycol, row)] = hb;
        hn[LHA(mycol, row + 8)] = hb;      // keep duplicate half in sync
        if (LAYER == 1) sm[reg] += h;
      }
    }
    // E) commit xg prefetch to lxg[nxt]
    if (hasN) {
      *(uint4*)&lxg[nxt][tid * 8] = p0;
      if (tid < 256) *(uint4*)&lxg[nxt][4096 + tid * 8] = p1;
    }
    __syncthreads();
    cur = nxt;
  }

  // final h1out block (h(Ta))
  if (LAYER == 0 && tid < 256) {
    int row = tid >> 5, c0 = (tid & 31) * 8;
    uint4 hv = *(const uint4*)&lh[cur][(((c0 >> 5) * 64 + ((c0 >> 3) & 3) * 16 + row) * 8)];
    *(uint4*)&h1out[((size_t)(Ta - 1) * NB + g0 + row) * DF + c0] = hv;
  }
  if (save) {
#pragma unroll
    for (int reg = 0; reg < 4; ++reg) {
      int row = rlow + reg;
      hstate[(size_t)(g0 + row) * DF + mycol] = hp[reg];
    }
  }
  if (LAYER == 1) {
    if (last) {
#pragma unroll
      for (int reg = 0; reg < 4; ++reg) {
        int row = rlow + reg;
        outp[(size_t)(g0 + row) * DF + mycol] = sm[reg] * (1.0f / 96.0f);
      }
    } else {
#pragma unroll
      for (int reg = 0; reg < 4; ++reg) {
        int row = rlow + reg;
        sumstate[(size_t)(g0 + row) * DF + mycol] = sm[reg];
      }
    }
  }
}

// ------------------------------- host launcher ------------------------------
extern "C" void kernel_launch(void* const* d_in, const int* in_sizes, int n_in,
                              void* d_out, int out_size, void* d_ws, size_t ws_size,
                              hipStream_t stream) {
  (void)n_in; (void)out_size;
  const float* x    = (const float*)d_in[0];
  const float* ts   = (const float*)d_in[1];
  const float* wih0 = (const float*)d_in[2];
  const float* whh0 = (const float*)d_in[3];
  const float* bih0 = (const float*)d_in[4];
  const float* bhh0 = (const float*)d_in[5];
  const float* wih1 = (const float*)d_in[6];
  const float* whh1 = (const float*)d_in[7];
  const float* bih1 = (const float*)d_in[8];
  const float* bhh1 = (const float*)d_in[9];
  const int*   idx  = (const int*)d_in[10];
  float* out = (float*)d_out;
  const int E = in_sizes[0] / DF;

  char* wsb = (char*)d_ws;
  size_t off = 0;
  auto carve = [&](size_t bytes) -> char* {
    off = (off + 255) & ~(size_t)255;
    char* p = wsb + off;
    off += bytes;
    return p;
  };
  int* offs = (int*)carve((size_t)NB * 4);
  int* cntp = (int*)carve((size_t)NB * 4);
  int* perm = (int*)carve((size_t)NB * LT * 4);
  unsigned short* wfrag = (unsigned short*)carve((size_t)4 * 196608 * 2);
  float* h0s  = (float*)carve((size_t)NB * DF * 4);
  float* h1s  = (float*)carve((size_t)NB * DF * 4);
  float* sums = (float*)carve((size_t)NB * DF * 4);
  size_t fixedBytes = off;

  const size_t perT = (size_t)NB * DF * 2 + 2 * (size_t)NB * NG * 2;  // 7,340,032 B
  int Tc = 1;
  if (ws_size > fixedBytes + 4096) {
    size_t t = (ws_size - fixedBytes - 4096) / perT;
    Tc = (int)(t > 96 ? 96 : (t < 1 ? 1 : t));
  }
  unsigned short* h1buf = (unsigned short*)carve((size_t)Tc * NB * DF * 2);
  unsigned short* xgA   = (unsigned short*)carve((size_t)Tc * NB * NG * 2);
  unsigned short* xgB   = (unsigned short*)carve((size_t)Tc * NB * NG * 2);

  k_offsets<<<8, 256, 0, stream>>>(idx, E, offs, cntp);
  k_rank<<<NB, 128, 0, stream>>>(ts, offs, cntp, perm);
  k_packw<<<384, 256, 0, stream>>>(wih0, whh0, wih1, whh1, wfrag);

  for (int t0 = 0; t0 < LT; t0 += Tc) {
    int Ta = (LT - t0 < Tc) ? (LT - t0) : Tc;
    int first = (t0 == 0);
    int save = (t0 + Ta < LT);
    int last = (t0 + Ta == LT);
    int slabs = Ta * 32;
    // jbN: persistent-block stride; 6*jbN blocks, all co-resident (2/CU)
    int jbN = slabs < 85 ? slabs : 85;
    // layer 0 input projection (gathered x, pads -> b_ih)
    k_xgemm<0><<<dim3(6 * jbN), 256, 0, stream>>>(
        x, (const unsigned short*)nullptr, perm, t0, slabs, jbN, wfrag, bih0, xgA);
    // layer 0 recurrence -> h1buf
    k_recur<0><<<256, 512, 0, stream>>>(
        wfrag + 1 * 196608, bhh0, xgA, Ta, h0s, first, save, h1buf,
        (float*)nullptr, (float*)nullptr, 0);
    // layer 1 input projection (dense h1)
    k_xgemm<1><<<dim3(6 * jbN), 256, 0, stream>>>(
        (const float*)nullptr, h1buf, (const int*)nullptr, 0, slabs, jbN,
        wfrag + 2 * 196608, bih1, xgB);
    // layer 1 recurrence -> mean accumulation / output
    k_recur<1><<<256, 512, 0, stream>>>(
        wfrag + 3 * 196608, bhh1, xgB, Ta, h1s, first, save,
        (unsigned short*)nullptr, sums, out, last);
  }
}